// Round 11
// baseline (338.919 us; speedup 1.0000x reference)
//
#include <hip/hip_runtime.h>

// BinaryLinear: out[32768,1024] = x[32768,1024] @ (sign(W)*scale)^T + b
// R11: fuse f32->bf16 conversion INTO the 8-phase GEMM (cvt_kernel deleted).
//   A (x) is reg-staged: float4 loads (pre-swizzled source col) -> RNE f2bf
//   -> ds_write_b128 at LINEAR dest (base+lane*16), identical layout to the
//   R10 global_load_lds placement, so the verified read swizzle is unchanged.
//   B (Wb) keeps global_load_lds + counted-vmcnt. Saves cvt (~32us + 192MB).

typedef short short8 __attribute__((ext_vector_type(8)));
typedef float f32x4 __attribute__((ext_vector_type(4)));

#define BATCH 32768
#define IN_F  1024
#define OUT_F 1024
#define EPS   1e-6f

__device__ __forceinline__ ushort f2bf(float f) {
  unsigned u = __builtin_bit_cast(unsigned, f);
  u += 0x7FFFu + ((u >> 16) & 1u);   // round-to-nearest-even
  return (ushort)(u >> 16);
}

// async global->LDS, 16B/lane; LDS dest = wave-uniform base + lane*16
__device__ __forceinline__ void gload_lds16(const void* g, void* l) {
  __builtin_amdgcn_global_load_lds(
      (const __attribute__((address_space(1))) unsigned*)g,
      (__attribute__((address_space(3))) unsigned*)l, 16, 0, 0);
}

// ---- Kernel 1: per-row scale + binarized bf16 weights ----
__global__ void bin_kernel(const float* __restrict__ W,
                           ushort* __restrict__ Wb,
                           float* __restrict__ scale) {
  int row = blockIdx.x * 4 + (threadIdx.x >> 6);
  int t = threadIdx.x & 63;
  const float4* wr = (const float4*)(W + (size_t)row * IN_F);
  ushort4* wb = (ushort4*)(Wb + (size_t)row * IN_F);
  float s = 0.f;
#pragma unroll
  for (int i = 0; i < 4; ++i) {
    float4 v = wr[i * 64 + t];
    ushort4 u;
    u.x = (v.x >= 0.f) ? 0x3F80 : 0xBF80;
    u.y = (v.y >= 0.f) ? 0x3F80 : 0xBF80;
    u.z = (v.z >= 0.f) ? 0x3F80 : 0xBF80;
    u.w = (v.w >= 0.f) ? 0x3F80 : 0xBF80;
    wb[i * 64 + t] = u;
    s += fabsf(v.x) + fabsf(v.y) + fabsf(v.z) + fabsf(v.w);
  }
#pragma unroll
  for (int o = 32; o > 0; o >>= 1) s += __shfl_down(s, o);
  if (t == 0) scale[row] = fmaxf(s * (1.0f / (float)IN_F), EPS);
}

// ---- 8-phase GEMM helpers ----
__device__ __forceinline__ void rd4(short8 (*dst)[2], const char* base,
                                    int c0, int c1) {
#pragma unroll
  for (int m = 0; m < 4; ++m) {
    dst[m][0] = *(const short8*)(base + m * 2048 + c0);
    dst[m][1] = *(const short8*)(base + m * 2048 + c1);
  }
}
__device__ __forceinline__ void rd2(short8 (*dst)[2], const char* base,
                                    int c0, int c1) {
#pragma unroll
  for (int n = 0; n < 2; ++n) {
    dst[n][0] = *(const short8*)(base + n * 2048 + c0);
    dst[n][1] = *(const short8*)(base + n * 2048 + c1);
  }
}
template <int MB, int NB>
__device__ __forceinline__ void mmq(f32x4 (*acc)[4], const short8 (*a)[2],
                                    const short8 (*b)[2]) {
#pragma unroll
  for (int ks = 0; ks < 2; ++ks)
#pragma unroll
    for (int m = 0; m < 4; ++m)
#pragma unroll
      for (int n = 0; n < 2; ++n)
        acc[MB + m][NB + n] = __builtin_amdgcn_mfma_f32_16x16x32_bf16(
            a[m][ks], b[n][ks], acc[MB + m][NB + n], 0, 0, 0);
}

#define FENCE() do { __builtin_amdgcn_sched_barrier(0); \
                     asm volatile("" ::: "memory"); } while (0)
#define BAR()   do { FENCE(); __builtin_amdgcn_s_barrier(); FENCE(); } while (0)
#define MFMA_SEC(stmt) do { BAR(); __builtin_amdgcn_s_setprio(1); stmt; \
                            __builtin_amdgcn_s_setprio(0); BAR(); } while (0)

// ---- Kernel 2: 256x256 8-phase bf16 MFMA GEMM, fused f32->bf16 A-stage ----
// A = x [32768][1024] f32 (converted in-kernel), B = Wb [1024][1024] bf16.
// LDS: A buf0 [0,32K) A buf1 [32K,64K) B buf0 [64K,96K) B buf1 [96K,128K).
// Per buffer: [256 rows][64 k] bf16, row stride 128 B, byte^((row&7)<<4)
// swizzle realized by pre-swizzled SOURCE column + linear dest (rule #21).
__global__ __launch_bounds__(512, 2) void gemm8pf(
    const float* __restrict__ X, const ushort* __restrict__ Wb,
    const float* __restrict__ scale, const float* __restrict__ bias,
    float* __restrict__ out) {
  __shared__ __align__(16) char L[131072];

  // T1: 512 blocks, 8 XCDs x 64; within XCD: nt fastest (x-panel L2 reuse)
  int bid = blockIdx.x;
  int g = (bid & 7) * 64 + (bid >> 3);
  int mt = g >> 2, nt = g & 3;
  int rowBase = mt * 256, colBase = nt * 256;

  int tid = threadIdx.x, lane = tid & 63, w = tid >> 6;
  int wm = w >> 2, wn = w & 3;          // wave grid 2M x 4N; 128x64 out/wave

  int baseA = (wm * 128 + (lane & 15)) * 128;
  int baseB = 65536 + (wn * 64 + (lane & 15)) * 128;
  int c0 = ((lane >> 4) * 16) ^ ((lane & 7) << 4);   // kslice 0
  int c1 = c0 ^ 64;                                   // kslice 1
  // staging: lane covers row (slab+srl), source col-group (lane&7)^srl
  int srl = lane >> 3;
  int scb = ((lane & 7) ^ srl) * 8;                   // element offset
  int bu0 = (w & 3) * 8 + (w >> 2) * 64;              // B wave row0
  const float*  gAf = X  + ((size_t)rowBase + srl) * IN_F + scb;
  const ushort* gB  = Wb + ((size_t)colBase + srl) * IN_F + scb;

// A: issue 4 float4 (2 slabs) for unit (r0a,r0b) at K-tile kt
#define ALOAD(v0, v1, v2, v3, kt, r0a, r0b) do { \
    const float* p0 = gAf + (size_t)(r0a) * IN_F + (kt) * 64; \
    const float* p1 = gAf + (size_t)(r0b) * IN_F + (kt) * 64; \
    v0 = *(const float4*)p0; v1 = *(const float4*)(p0 + 4); \
    v2 = *(const float4*)p1; v3 = *(const float4*)(p1 + 4); } while (0)
// A: convert one slab (2 float4) -> ds_write_b128 at linear dest
#define CVTW1(v0, v1, dstOff) do { short8 u; \
    u[0] = (short)f2bf(v0.x); u[1] = (short)f2bf(v0.y); \
    u[2] = (short)f2bf(v0.z); u[3] = (short)f2bf(v0.w); \
    u[4] = (short)f2bf(v1.x); u[5] = (short)f2bf(v1.y); \
    u[6] = (short)f2bf(v1.z); u[7] = (short)f2bf(v1.w); \
    *(short8*)(L + (dstOff) + lane * 16) = u; } while (0)
#define STB(bufOff, kt, row0) \
  gload_lds16(gB + (size_t)(row0) * IN_F + (kt) * 64, \
              L + 65536 + (bufOff) + (row0) * 128)

  f32x4 acc[8][4];
#pragma unroll
  for (int m = 0; m < 8; ++m)
#pragma unroll
    for (int n = 0; n < 4; ++n) acc[m][n] = (f32x4){0.f, 0.f, 0.f, 0.f};

  float4 xa0, xa1, xa2, xa3;   // u0 staging regs
  float4 xb0, xb1, xb2, xb3;   // u1 staging regs
  float4 pa0, pa1, pa2, pa3, pb0, pb1, pb2, pb3;

  // ---- prologue: tile0 -> buf0, tile1 -> buf1 ----
  ALOAD(pa0, pa1, pa2, pa3, 0, w * 8, 128 + w * 8);        // t0 u0
  ALOAD(pb0, pb1, pb2, pb3, 0, 64 + w * 8, 192 + w * 8);   // t0 u1
  STB(0, 0, bu0); STB(0, 0, bu0 + 128);
  STB(0, 0, bu0 + 32); STB(0, 0, bu0 + 160);
  ALOAD(xa0, xa1, xa2, xa3, 1, w * 8, 128 + w * 8);        // t1 u0
  ALOAD(xb0, xb1, xb2, xb3, 1, 64 + w * 8, 192 + w * 8);   // t1 u1
  STB(32768, 1, bu0); STB(32768, 1, bu0 + 128);
  STB(32768, 1, bu0 + 32); STB(32768, 1, bu0 + 160);
  CVTW1(pa0, pa1, (w * 8) * 128);
  CVTW1(pa2, pa3, (128 + w * 8) * 128);
  CVTW1(pb0, pb1, (64 + w * 8) * 128);
  CVTW1(pb2, pb3, (192 + w * 8) * 128);
  CVTW1(xa0, xa1, 32768 + (w * 8) * 128);
  CVTW1(xa2, xa3, 32768 + (128 + w * 8) * 128);
  CVTW1(xb0, xb1, 32768 + (64 + w * 8) * 128);
  CVTW1(xb2, xb3, 32768 + (192 + w * 8) * 128);
  asm volatile("s_waitcnt lgkmcnt(0)" ::: "memory");   // A writes landed
  asm volatile("s_waitcnt vmcnt(4)");                  // B-t0 DMA done
  BAR();

  short8 aLo[4][2], aHi[4][2], bb[2][2];

  for (int it = 0; it < 8; ++it) {
    int kt2 = (2 * it + 2) & 15;        // wraps to dead-but-valid on last it
    int kt3 = (2 * it + 3) & 15;

    // ======== X half: tile 2it in buf0 ========
    // p1: 12 ds_reads; issue A-X' u0 loads
    rd4(aLo, L + baseA, c0, c1);
    rd2(bb, L + baseB, c0, c1);
    ALOAD(xa0, xa1, xa2, xa3, kt2, w * 8, 128 + w * 8);
    MFMA_SEC((mmq<0, 0>(acc, aLo, bb)));
    // p2: write A-X' u0 (rows just freed by p1); 8 ds_reads
    CVTW1(xa0, xa1, (w * 8) * 128);
    CVTW1(xa2, xa3, (128 + w * 8) * 128);
    rd4(aHi, L + baseA + 8192, c0, c1);
    MFMA_SEC((mmq<4, 0>(acc, aHi, bb)));
    // p3: issue A-X' u1 loads; stage B-X' u0; 4 ds_reads
    ALOAD(xb0, xb1, xb2, xb3, kt2, 64 + w * 8, 192 + w * 8);
    STB(0, kt2, bu0); STB(0, kt2, bu0 + 128);
    rd2(bb, L + baseB + 4096, c0, c1);
    MFMA_SEC((mmq<4, 2>(acc, aHi, bb)));
    // p4: write A-X' u1 (rows freed by p2); drain writes; vmcnt guard
    CVTW1(xb0, xb1, (64 + w * 8) * 128);
    CVTW1(xb2, xb3, (192 + w * 8) * 128);
    asm volatile("s_waitcnt lgkmcnt(0)" ::: "memory");
    asm volatile("s_waitcnt vmcnt(6)");
    MFMA_SEC((mmq<0, 2>(acc, aLo, bb)));

    // ======== Y half: tile 2it+1 in buf1 ========
    // p5: 12 ds_reads (buf1); issue A-Y' u0 loads; stage B-X' u1
    rd4(aLo, L + 32768 + baseA, c0, c1);
    rd2(bb, L + 32768 + baseB, c0, c1);
    ALOAD(xa0, xa1, xa2, xa3, kt3, w * 8, 128 + w * 8);
    STB(0, kt2, bu0 + 32); STB(0, kt2, bu0 + 160);
    MFMA_SEC((mmq<0, 0>(acc, aLo, bb)));
    // p6: write A-Y' u0; 8 ds_reads
    CVTW1(xa0, xa1, 32768 + (w * 8) * 128);
    CVTW1(xa2, xa3, 32768 + (128 + w * 8) * 128);
    rd4(aHi, L + 32768 + baseA + 8192, c0, c1);
    MFMA_SEC((mmq<4, 0>(acc, aHi, bb)));
    // p7: issue A-Y' u1 loads; stage B-Y' u0; 4 ds_reads
    ALOAD(xb0, xb1, xb2, xb3, kt3, 64 + w * 8, 192 + w * 8);
    STB(32768, kt3, bu0); STB(32768, kt3, bu0 + 128);
    rd2(bb, L + 32768 + baseB + 4096, c0, c1);
    MFMA_SEC((mmq<4, 2>(acc, aHi, bb)));
    // p8: write A-Y' u1; stage B-Y' u1; drain writes; vmcnt guard
    CVTW1(xb0, xb1, 32768 + (64 + w * 8) * 128);
    CVTW1(xb2, xb3, 32768 + (192 + w * 8) * 128);
    STB(32768, kt3, bu0 + 32); STB(32768, kt3, bu0 + 160);
    asm volatile("s_waitcnt lgkmcnt(0)" ::: "memory");
    asm volatile("s_waitcnt vmcnt(6)");
    MFMA_SEC((mmq<0, 2>(acc, aLo, bb)));
  }

  asm volatile("s_waitcnt vmcnt(0)");   // drain stale prefetches

  // epilogue: C/D layout col=lane&15, row=(lane>>4)*4+j (m89-verified)
#pragma unroll
  for (int n = 0; n < 4; ++n) {
    int col = colBase + wn * 64 + n * 16 + (lane & 15);
    float sc = scale[col];
    float bs = bias[col];
#pragma unroll
    for (int m = 0; m < 8; ++m) {
      int r0 = rowBase + wm * 128 + m * 16 + ((lane >> 4) << 2);
#pragma unroll
      for (int j = 0; j < 4; ++j)
        out[(size_t)(r0 + j) * OUT_F + col] = acc[m][n][j] * sc + bs;
    }
  }
#undef ALOAD
#undef CVTW1
#undef STB
}

// ---- Fallback GEMM (R1 structure, reg-staged f32->bf16) ----
__global__ void gemm_kernel(const float* __restrict__ X,
                            const ushort* __restrict__ Wb,
                            const float* __restrict__ scale,
                            const float* __restrict__ bias,
                            float* __restrict__ out) {
  __shared__ __align__(16) ushort lA[128 * 32];
  __shared__ __align__(16) ushort lB[128 * 32];
  int bid = blockIdx.x;
  int g = (bid & 7) * 256 + (bid >> 3);
  int mt = g >> 3, nt = g & 7;
  int rowBase = mt * 128, colBase = nt * 128;
  int t = threadIdx.x, lane = t & 63, wave = t >> 6;
  int wr = wave >> 1, wc = wave & 1;
  f32x4 acc[4][4];
#pragma unroll
  for (int m = 0; m < 4; ++m)
#pragma unroll
    for (int n = 0; n < 4; ++n) acc[m][n] = (f32x4){0.f, 0.f, 0.f, 0.f};
  for (int kk = 0; kk < IN_F / 32; ++kk) {
    int k0 = kk * 32;
    __syncthreads();
#pragma unroll
    for (int i = 0; i < 2; ++i) {
      int idx = t + 256 * i;
      int r = idx >> 2, c16 = idx & 3;
      const float4* gp =
          (const float4*)(X + (size_t)(rowBase + r) * IN_F + k0 + c16 * 8);
      float4 v0 = gp[0];
      float4 v1 = gp[1];
      short8 u;
      u[0] = (short)f2bf(v0.x); u[1] = (short)f2bf(v0.y);
      u[2] = (short)f2bf(v0.z); u[3] = (short)f2bf(v0.w);
      u[4] = (short)f2bf(v1.x); u[5] = (short)f2bf(v1.y);
      u[6] = (short)f2bf(v1.z); u[7] = (short)f2bf(v1.w);
      int off = (r * 32 + c16 * 8) ^ ((r & 7) << 3);
      *(short8*)(&lA[off]) = u;
      const short8* gp2 =
          (const short8*)(Wb + (size_t)(colBase + r) * IN_F + k0 + c16 * 8);
      *(short8*)(&lB[off]) = *gp2;
    }
    __syncthreads();
    short8 af[4], bfr[4];
#pragma unroll
    for (int m = 0; m < 4; ++m) {
      int r = wr * 64 + m * 16 + (lane & 15);
      int off = (r * 32 + (lane >> 4) * 8) ^ ((r & 7) << 3);
      af[m] = *(const short8*)(&lA[off]);
    }
#pragma unroll
    for (int n = 0; n < 4; ++n) {
      int r = wc * 64 + n * 16 + (lane & 15);
      int off = (r * 32 + (lane >> 4) * 8) ^ ((r & 7) << 3);
      bfr[n] = *(const short8*)(&lB[off]);
    }
#pragma unroll
    for (int m = 0; m < 4; ++m)
#pragma unroll
      for (int n = 0; n < 4; ++n)
        acc[m][n] = __builtin_amdgcn_mfma_f32_16x16x32_bf16(
            af[m], bfr[n], acc[m][n], 0, 0, 0);
  }
#pragma unroll
  for (int n = 0; n < 4; ++n) {
    int col = colBase + wc * 64 + n * 16 + (lane & 15);
    float sc = scale[col];
    float bs = bias[col];
#pragma unroll
    for (int m = 0; m < 4; ++m) {
      int r0 = rowBase + wr * 64 + m * 16 + ((lane >> 4) << 2);
#pragma unroll
      for (int j = 0; j < 4; ++j)
        out[(size_t)(r0 + j) * OUT_F + col] = acc[m][n][j] * sc + bs;
    }
  }
}

extern "C" void kernel_launch(void* const* d_in, const int* in_sizes, int n_in,
                              void* d_out, int out_size, void* d_ws,
                              size_t ws_size, hipStream_t stream) {
  const float* x = (const float*)d_in[0];
  const float* W = (const float*)d_in[1];
  const float* b = (const float*)d_in[2];
  float* out = (float*)d_out;

  float* scale = (float*)d_ws;                               // 4 KB
  ushort* Wb = (ushort*)((char*)d_ws + 4096);                // 2 MB
  const size_t need = 4096 + 2097152;

  bin_kernel<<<OUT_F / 4, 256, 0, stream>>>(W, Wb, scale);

  if (ws_size >= need) {
    gemm8pf<<<(BATCH / 256) * (OUT_F / 256), 512, 0, stream>>>(x, Wb, scale,
                                                               b, out);
  } else {
    gemm_kernel<<<(BATCH / 128) * (OUT_F / 128), 256, 0, stream>>>(
        x, Wb, scale, b, out);
  }
}